// Round 11
// baseline (123.866 us; speedup 1.0000x reference)
//
#include <hip/hip_runtime.h>
#include <hip/hip_bf16.h>
#include <math.h>

#define NN 256
#define DD 128
#define EE 64
#define APAD 392   // kernel2 A row stride (ushorts)
#define RPAD 136   // kernel2 rbuf row stride (ushorts)

typedef __attribute__((ext_vector_type(8))) short short8;
typedef __attribute__((ext_vector_type(4))) float f32x4;

static __device__ __forceinline__ unsigned short f2bf(float f) {
    __hip_bfloat16 b = __float2bfloat16(f);
    return *reinterpret_cast<unsigned short*>(&b);
}

static __device__ __forceinline__ float sigm(float l) {
    return __fdividef(1.f, 1.f + __expf(-l));
}

// bf16 B-fragment for mfma_16x16x32 from row-major f32 B[K][128] in global.
static __device__ __forceinline__ short8 ldb(const float* __restrict__ B, int kbase, int d) {
    unsigned short tmp[8];
    #pragma unroll
    for (int j = 0; j < 8; ++j) tmp[j] = f2bf(B[(kbase + j) * DD + d]);
    return *(const short8*)tmp;
}

// ---------------- Kernel 1: gate + masked aggregation (+ u1t/u2t pack) -------
// R10 hot-loop structure (proven 39.8 us, spill-free), now TWO (b,i) per block:
// weight prologue (w1e, W2 fragments, nb2, pack slice) paid once for both rows;
// hot loop runs as two sequential passes, qa/qb register cache reloaded from
// sh_q4[pass] between passes so the per-lane live set is UNCHANGED (R7/R9:
// any live-set growth spills >60 MB scratch — do not grow it).
__global__ __launch_bounds__(256, 4)
void ecgc_gate(const float* __restrict__ h_g,
               const float* __restrict__ ef_g,
               const int*   __restrict__ mask_g,
               const float* __restrict__ W1_g,
               const float* __restrict__ b1_g,
               const float* __restrict__ W2_g,
               const float* __restrict__ b2_g,
               const float* __restrict__ U1_g,
               const float* __restrict__ U2_g,
               float*          __restrict__ aggf,
               unsigned short* __restrict__ u1t,
               unsigned short* __restrict__ u2t)
{
    const int bi0  = blockIdx.x * 2;
    const int t    = threadIdx.x;
    const int lane = t & 63;
    const int w    = t >> 6;
    const int m16  = lane & 15;
    const int quad = lane >> 4;

    __shared__ __align__(16) float sh_ef4[2][NN * 4];   // 8 KB
    __shared__ __align__(16) float sh_q4[2][EE * 4];    // 2 KB {base,w10,w11,w12}
    __shared__ float sh_basep[2][4 * EE];               // 2 KB
    __shared__ float sh_w1e[3 * EE];
    __shared__ int   sh_jlist[2][NN], sh_wcnt[2][4], sh_cnt[2];

    // ---- u1t/u2t bf16 pack slice: 65536 elems over 1024 blocks ----
    if (t < 64) {
        const int flat = blockIdx.x * 64 + t;
        if (flat < 384 * DD) {
            const int d = flat / 384, k = flat - d * 384;
            u1t[flat] = f2bf(U1_g[k * DD + d]);
        } else {
            const int f2i = flat - 384 * DD;
            const int d = f2i >> 7, k = f2i & 127;
            u2t[f2i] = f2bf(U2_g[k * DD + d]);
        }
    }

    // ---- stage (both rows) ----
    #pragma unroll
    for (int p = 0; p < 2; ++p) {
        const float* efr = ef_g + (size_t)(bi0 + p) * NN * 3;
        sh_ef4[p][t * 4 + 0] = efr[t * 3 + 0];
        sh_ef4[p][t * 4 + 1] = efr[t * 3 + 1];
        sh_ef4[p][t * 4 + 2] = efr[t * 3 + 2];
        sh_ef4[p][t * 4 + 3] = 0.f;
    }
    if (t < 192) sh_w1e[t] = W1_g[(DD + (t >> 6)) * EE + (t & 63)];

    int mk[2], pre[2];
    #pragma unroll
    for (int p = 0; p < 2; ++p) {
        mk[p] = (mask_g[(bi0 + p) * NN + t] != 0) ? 1 : 0;
        const unsigned long long bal = __ballot(mk[p]);
        if (lane == 0) sh_wcnt[p][w] = __popcll(bal);
        pre[p] = __popcll(bal & ((1ull << lane) - 1ull));
    }

    // basep: thread (e = t&63) partial over d-range [w*32, w*32+32), both rows
    {
        const int e = t & 63;
        float a0 = 0.f, a1 = 0.f;
        #pragma unroll 8
        for (int d = w * 32; d < w * 32 + 32; ++d) {
            const float wv = W1_g[d * EE + e];
            a0 = fmaf(h_g[bi0 * DD + d],       wv, a0);
            a1 = fmaf(h_g[(bi0 + 1) * DD + d], wv, a1);
        }
        sh_basep[0][w * EE + e] = a0;
        sh_basep[1][w * EE + e] = a1;
    }

    // W2 B-fragments + b2 (shared by both rows)
    const int dstripe = w * 32;
    short8 bfrag[2][2];
    float  nb2[2];
    #pragma unroll
    for (int dt = 0; dt < 2; ++dt) {
        const int d = dstripe + 16 * dt + m16;
        nb2[dt] = b2_g[d];
        #pragma unroll
        for (int kh = 0; kh < 2; ++kh)
            bfrag[dt][kh] = ldb(W2_g, kh * 32 + quad * 8, d);
    }
    __syncthreads();   // barrier 1: wcnt/basep/w1e ready

    #pragma unroll
    for (int p = 0; p < 2; ++p) {
        int wbase = 0;
        for (int ww = 0; ww < w; ++ww) wbase += sh_wcnt[p][ww];
        if (mk[p]) sh_jlist[p][wbase + pre[p]] = t;
        if (t == 0) sh_cnt[p] = sh_wcnt[p][0] + sh_wcnt[p][1] + sh_wcnt[p][2] + sh_wcnt[p][3];
    }
    if (t < 2 * EE) {   // t<64 -> row 0, 64<=t<128 -> row 1
        const int p = t >> 6, e = t & 63;
        const float base = b1_g[e] + sh_basep[p][e] + sh_basep[p][EE + e] +
                           sh_basep[p][2 * EE + e] + sh_basep[p][3 * EE + e];
        sh_q4[p][e * 4 + 0] = base;
        sh_q4[p][e * 4 + 1] = sh_w1e[e];
        sh_q4[p][e * 4 + 2] = sh_w1e[EE + e];
        sh_q4[p][e * 4 + 3] = sh_w1e[2 * EE + e];
    }
    __syncthreads();   // barrier 2: jlist/q4 ready.  Passes are barrier-free.

    for (int pass = 0; pass < 2; ++pass) {
        const int bi = bi0 + pass;

        // per-lane register cache of {base,w1e} for this lane's 16 e-values
        f32x4 qa[8], qb[8];
        #pragma unroll
        for (int jj = 0; jj < 8; ++jj) {
            qa[jj] = *(const f32x4*)&sh_q4[pass][(quad * 8 + jj) * 4];
            qb[jj] = *(const f32x4*)&sh_q4[pass][(32 + quad * 8 + jj) * 4];
        }

        float hd2[2], flip[2];
        #pragma unroll
        for (int dt = 0; dt < 2; ++dt) {
            hd2[dt]  = h_g[bi * DD + dstripe + 16 * dt + m16];
            flip[dt] = (hd2[dt] >= 0.f) ? 1.f : -1.f;
        }

        const int cnt = sh_cnt[pass];
        const int njt = (cnt + 15) >> 4;

        float sum2[2] = {0.f, 0.f};
        float mm[2]   = {-3.0e38f, -3.0e38f};   // max over j of flip*logit

        for (int jt = 0; jt < njt; ++jt) {
            const int row = jt * 16 + m16;          // < 256 always
            int jl = sh_jlist[pass][row];
            jl = (row < cnt) ? jl : 0;              // clamp stale tail values
            const float4 efv = *(const float4*)&sh_ef4[pass][jl * 4];

            // A fragments in registers: a0 = e[quad*8..+8), a1 = e[32+quad*8..+8)
            union { short8 s; __hip_bfloat162 h2[4]; } ua, ub;
            #pragma unroll
            for (int p = 0; p < 4; ++p) {
                const f32x4 qa0 = qa[2 * p], qa1 = qa[2 * p + 1];
                const f32x4 qb0 = qb[2 * p], qb1 = qb[2 * p + 1];
                float2 va, vb;
                va.x = fmaxf(fmaf(efv.z, qa0[3], fmaf(efv.y, qa0[2], fmaf(efv.x, qa0[1], qa0[0]))), 0.f);
                va.y = fmaxf(fmaf(efv.z, qa1[3], fmaf(efv.y, qa1[2], fmaf(efv.x, qa1[1], qa1[0]))), 0.f);
                vb.x = fmaxf(fmaf(efv.z, qb0[3], fmaf(efv.y, qb0[2], fmaf(efv.x, qb0[1], qb0[0]))), 0.f);
                vb.y = fmaxf(fmaf(efv.z, qb1[3], fmaf(efv.y, qb1[2], fmaf(efv.x, qb1[1], qb1[0]))), 0.f);
                ua.h2[p] = __float22bfloat162_rn(va);
                ub.h2[p] = __float22bfloat162_rn(vb);
            }

            const bool tail = (jt == njt - 1) && (cnt & 15);
            #pragma unroll
            for (int dt = 0; dt < 2; ++dt) {
                f32x4 acc = {nb2[dt], nb2[dt], nb2[dt], nb2[dt]};
                acc = __builtin_amdgcn_mfma_f32_16x16x32_bf16(ua.s, bfrag[dt][0], acc, 0, 0, 0);
                acc = __builtin_amdgcn_mfma_f32_16x16x32_bf16(ub.s, bfrag[dt][1], acc, 0, 0, 0);
                if (!tail) {
                    #pragma unroll
                    for (int r = 0; r < 4; ++r) {
                        const float l = acc[r];
                        mm[dt] = fmaxf(mm[dt], l * flip[dt]);
                        sum2[dt] += sigm(l);
                    }
                } else {
                    #pragma unroll
                    for (int r = 0; r < 4; ++r) {
                        const bool v = (jt * 16 + quad * 4 + r) < cnt;
                        const float lx = v ? acc[r] : -3.0e38f;            // sigm -> 0
                        const float pf = v ? acc[r] * flip[dt] : -3.0e38f; // never wins max
                        mm[dt] = fmaxf(mm[dt], pf);
                        sum2[dt] += sigm(lx);
                    }
                }
            }
        }

        // cross-quad reduce; sigmoid applied once on the extreme logit (monotone)
        #pragma unroll
        for (int dt = 0; dt < 2; ++dt) {
            float s = sum2[dt], M = mm[dt];
            s += __shfl_xor(s, 16, 64);  s += __shfl_xor(s, 32, 64);
            M  = fmaxf(M,  __shfl_xor(M, 16, 64));  M  = fmaxf(M,  __shfl_xor(M, 32, 64));
            if (quad == 0) {
                const int d = dstripe + 16 * dt + m16;
                const float hd = hd2[dt];
                float mean = 0.f, amax = 0.f;
                if (cnt > 0) {
                    mean = hd * s * __fdividef(1.f, (float)cnt);
                    amax = hd * sigm(flip[dt] * M);   // flip=+1: max l; flip=-1: min l
                }
                aggf[bi * 256 + d]       = mean;
                aggf[bi * 256 + 128 + d] = amax;
            }
        }
    }
}

// ---------------- Kernel 2: batched update MLP + LayerNorm ----------------
// 16 rows/block, 128 blocks. B-matrices pre-packed bf16 by gate (u1t, u2t).
__global__ __launch_bounds__(256, 2)
void ecgc_upd(const float* __restrict__ h_g,
              const float* __restrict__ aggf,
              const unsigned short* __restrict__ u1t,
              const unsigned short* __restrict__ u2t,
              const float* __restrict__ b3_g,
              const float* __restrict__ b4_g,
              const float* __restrict__ gam_g,
              const float* __restrict__ bet_g,
              float*       __restrict__ out_g)
{
    const int bi0  = blockIdx.x * 16;
    const int t    = threadIdx.x;
    const int lane = t & 63;
    const int w    = t >> 6;
    const int m16  = lane & 15;
    const int quad = lane >> 4;

    __shared__ __align__(16) unsigned short shA[16 * APAD];
    __shared__ __align__(16) unsigned short rbuf[16 * RPAD];
    __shared__ float sh_s[4 * 16], sh_s2[4 * 16], sh_mu[16], sh_rs[16];

    {
        const int row = t >> 4, q = t & 15;
        const float* hrow = h_g  + (size_t)(bi0 + row) * DD;
        const float* wrow = aggf + (size_t)(bi0 + row) * 256;
        unsigned short tmp[24];
        #pragma unroll
        for (int c = 0; c < 24; ++c) {
            const int col = q * 24 + c;
            float v;
            if (col < 128)      v = hrow[col];
            else if (col < 256) v = wrow[col - 128];
            else                v = wrow[col - 256 + 128];
            tmp[c] = f2bf(v);
        }
        #pragma unroll
        for (int s8 = 0; s8 < 3; ++s8)
            *(short8*)&shA[row * APAD + q * 24 + s8 * 8] = *(const short8*)&tmp[s8 * 8];
    }
    __syncthreads();

    const int dstripe = w * 32;

    f32x4 acc[2];
    #pragma unroll
    for (int dt = 0; dt < 2; ++dt) {
        const float bb = b3_g[dstripe + dt * 16 + m16];
        acc[dt] = (f32x4){bb, bb, bb, bb};
    }
    for (int kk = 0; kk < 12; ++kk) {
        const short8 a0 = *(const short8*)&shA[m16 * APAD + kk * 32 + quad * 8];
        #pragma unroll
        for (int dt = 0; dt < 2; ++dt) {
            const int d = dstripe + dt * 16 + m16;
            const short8 b = *(const short8*)&u1t[(size_t)d * 384 + kk * 32 + quad * 8];
            acc[dt] = __builtin_amdgcn_mfma_f32_16x16x32_bf16(a0, b, acc[dt], 0, 0, 0);
        }
    }

    #pragma unroll
    for (int dt = 0; dt < 2; ++dt) {
        const int d = dstripe + dt * 16 + m16;
        #pragma unroll
        for (int r = 0; r < 4; ++r) {
            const int ro = quad * 4 + r;
            rbuf[ro * RPAD + d] = f2bf(fmaxf(acc[dt][r], 0.f));
        }
    }
    __syncthreads();

    f32x4 acc2[2];
    #pragma unroll
    for (int dt = 0; dt < 2; ++dt) {
        const float bb = b4_g[dstripe + dt * 16 + m16];
        acc2[dt] = (f32x4){bb, bb, bb, bb};
    }
    for (int kk = 0; kk < 4; ++kk) {
        const short8 a0 = *(const short8*)&rbuf[m16 * RPAD + kk * 32 + quad * 8];
        #pragma unroll
        for (int dt = 0; dt < 2; ++dt) {
            const int d = dstripe + dt * 16 + m16;
            const short8 b = *(const short8*)&u2t[(size_t)d * 128 + kk * 32 + quad * 8];
            acc2[dt] = __builtin_amdgcn_mfma_f32_16x16x32_bf16(a0, b, acc2[dt], 0, 0, 0);
        }
    }

    float xv[2][4];
    #pragma unroll
    for (int dt = 0; dt < 2; ++dt) {
        const int d = dstripe + dt * 16 + m16;
        #pragma unroll
        for (int r = 0; r < 4; ++r) {
            const int ro = quad * 4 + r;
            xv[dt][r] = h_g[(size_t)(bi0 + ro) * DD + d] + acc2[dt][r];
        }
    }

    #pragma unroll
    for (int r = 0; r < 4; ++r) {
        float s  = xv[0][r] + xv[1][r];
        float s2 = xv[0][r] * xv[0][r] + xv[1][r] * xv[1][r];
        #pragma unroll
        for (int off = 1; off < 16; off <<= 1) {
            s  += __shfl_xor(s,  off, 64);
            s2 += __shfl_xor(s2, off, 64);
        }
        if (m16 == 0) {
            const int ro = quad * 4 + r;
            sh_s[w * 16 + ro]  = s;
            sh_s2[w * 16 + ro] = s2;
        }
    }
    __syncthreads();
    if (t < 16) {
        const float S  = sh_s[t]  + sh_s[16 + t]  + sh_s[32 + t]  + sh_s[48 + t];
        const float S2 = sh_s2[t] + sh_s2[16 + t] + sh_s2[32 + t] + sh_s2[48 + t];
        const float mu  = S * (1.f / 128.f);
        const float var = S2 * (1.f / 128.f) - mu * mu;
        sh_mu[t] = mu;
        sh_rs[t] = rsqrtf(var + 1e-5f);
    }
    __syncthreads();

    #pragma unroll
    for (int dt = 0; dt < 2; ++dt) {
        const int d = dstripe + dt * 16 + m16;
        const float ga = gam_g[d], be = bet_g[d];
        #pragma unroll
        for (int r = 0; r < 4; ++r) {
            const int ro = quad * 4 + r;
            out_g[(size_t)(bi0 + ro) * DD + d] =
                (xv[dt][r] - sh_mu[ro]) * sh_rs[ro] * ga + be;
        }
    }
}

extern "C" void kernel_launch(void* const* d_in, const int* in_sizes, int n_in,
                              void* d_out, int out_size, void* d_ws, size_t ws_size,
                              hipStream_t stream) {
    float* aggf = (float*)d_ws;                                    // 2 MB
    unsigned short* u1t = (unsigned short*)((char*)d_ws + (size_t)2048 * 256 * 4);
    unsigned short* u2t = u1t + 384 * DD;                          // +96 KB
    ecgc_gate<<<(8 * NN) / 2, 256, 0, stream>>>(
        (const float*)d_in[0],   // h
        (const float*)d_in[1],   // edge_feats
        (const int*)d_in[2],     // adj_mask
        (const float*)d_in[3],   // W1
        (const float*)d_in[4],   // b1
        (const float*)d_in[5],   // W2
        (const float*)d_in[6],   // b2
        (const float*)d_in[7],   // U1
        (const float*)d_in[9],   // U2
        aggf, u1t, u2t);
    ecgc_upd<<<(8 * NN) / 16, 256, 0, stream>>>(
        (const float*)d_in[0],   // h
        aggf, u1t, u2t,
        (const float*)d_in[8],   // b3
        (const float*)d_in[10],  // b4
        (const float*)d_in[11],  // gamma
        (const float*)d_in[12],  // beta
        (float*)d_out);
}

// Round 12
// 121.650 us; speedup vs baseline: 1.0182x; 1.0182x over previous
//
#include <hip/hip_runtime.h>
#include <hip/hip_bf16.h>
#include <math.h>

#define NN 256
#define DD 128
#define EE 64
#define APAD 392   // kernel2 A row stride (ushorts)
#define RPAD 136   // kernel2 rbuf row stride (ushorts)

typedef __attribute__((ext_vector_type(8))) short short8;
typedef __attribute__((ext_vector_type(4))) float f32x4;

static __device__ __forceinline__ unsigned short f2bf(float f) {
    __hip_bfloat16 b = __float2bfloat16(f);
    return *reinterpret_cast<unsigned short*>(&b);
}

static __device__ __forceinline__ float sigm(float l) {
    return __fdividef(1.f, 1.f + __expf(-l));
}

// bf16 B-fragment for mfma_16x16x32 from row-major f32 B[K][128] in global.
static __device__ __forceinline__ short8 ldb(const float* __restrict__ B, int kbase, int d) {
    unsigned short tmp[8];
    #pragma unroll
    for (int j = 0; j < 8; ++j) tmp[j] = f2bf(B[(kbase + j) * DD + d]);
    return *(const short8*)tmp;
}

// ---------------- Kernel 1: gate + masked aggregation (+ u1t/u2t pack) -------
// R10 structure == best of 7 variants (39.8 us, spill-free). One block per
// (b,i); wave w owns d-stripe [32w,32w+32), ALL j; T rows built in registers,
// duplicated x4 across waves. Grid 2048 blocks = exactly full residency
// (8 waves/SIMD at VGPR=64) — R11's 2-bi merge halved parallelism and lost.
// R7 (x1 dedup) / R9 (x2 dedup) spilled >60 MB scratch: do NOT grow the
// per-lane live set.
__global__ __launch_bounds__(256, 4)
void ecgc_gate(const float* __restrict__ h_g,
               const float* __restrict__ ef_g,
               const int*   __restrict__ mask_g,
               const float* __restrict__ W1_g,
               const float* __restrict__ b1_g,
               const float* __restrict__ W2_g,
               const float* __restrict__ b2_g,
               const float* __restrict__ U1_g,
               const float* __restrict__ U2_g,
               float*          __restrict__ aggf,
               unsigned short* __restrict__ u1t,
               unsigned short* __restrict__ u2t)
{
    const int bi   = blockIdx.x;
    const int t    = threadIdx.x;
    const int lane = t & 63;
    const int w    = t >> 6;
    const int m16  = lane & 15;
    const int quad = lane >> 4;

    __shared__ __align__(16) float sh_ef4[NN * 4];   // 4 KB
    __shared__ __align__(16) float sh_q4[EE * 4];    // 1 KB {base,w10,w11,w12}
    __shared__ float sh_basep[4 * EE];               // 1 KB
    __shared__ float sh_w1e[3 * EE];
    __shared__ int   sh_jlist[NN], sh_wcnt[4], sh_cnt;

    // ---- u1t/u2t bf16 pack slice: 65536 elems over 2048 blocks ----
    if (t < 32) {
        const int flat = bi * 32 + t;
        if (flat < 384 * DD) {
            const int d = flat / 384, k = flat - d * 384;
            u1t[flat] = f2bf(U1_g[k * DD + d]);
        } else {
            const int f2i = flat - 384 * DD;
            const int d = f2i >> 7, k = f2i & 127;
            u2t[f2i] = f2bf(U2_g[k * DD + d]);
        }
    }

    // ---- stage ----
    {
        const float* efr = ef_g + (size_t)bi * NN * 3;
        sh_ef4[t * 4 + 0] = efr[t * 3 + 0];
        sh_ef4[t * 4 + 1] = efr[t * 3 + 1];
        sh_ef4[t * 4 + 2] = efr[t * 3 + 2];
        sh_ef4[t * 4 + 3] = 0.f;
    }
    if (t < 192) sh_w1e[t] = W1_g[(DD + (t >> 6)) * EE + (t & 63)];

    const int mk = (mask_g[bi * NN + t] != 0) ? 1 : 0;
    const unsigned long long bal = __ballot(mk);
    if (lane == 0) sh_wcnt[w] = __popcll(bal);
    const int pre = __popcll(bal & ((1ull << lane) - 1ull));

    // basep: thread (e = t&63) partial over d-range [w*32, w*32+32)
    {
        const int e = t & 63;
        float acc = 0.f;
        #pragma unroll 8
        for (int d = w * 32; d < w * 32 + 32; ++d)
            acc = fmaf(h_g[bi * DD + d], W1_g[d * EE + e], acc);
        sh_basep[w * EE + e] = acc;
    }

    // W2 B-fragments; b2 for C-init; h_d and sign-flip per d-tile
    const int dstripe = w * 32;
    short8 bfrag[2][2];
    float  nb2[2], hd2[2], flip[2];
    #pragma unroll
    for (int dt = 0; dt < 2; ++dt) {
        const int d = dstripe + 16 * dt + m16;
        nb2[dt] = b2_g[d];
        hd2[dt] = h_g[bi * DD + d];
        flip[dt] = (hd2[dt] >= 0.f) ? 1.f : -1.f;
        #pragma unroll
        for (int kh = 0; kh < 2; ++kh)
            bfrag[dt][kh] = ldb(W2_g, kh * 32 + quad * 8, d);
    }
    __syncthreads();   // barrier 1: wcnt/basep/w1e ready

    {
        int wbase = 0;
        for (int ww = 0; ww < w; ++ww) wbase += sh_wcnt[ww];
        if (mk) sh_jlist[wbase + pre] = t;
        if (t == 0) sh_cnt = sh_wcnt[0] + sh_wcnt[1] + sh_wcnt[2] + sh_wcnt[3];
    }
    if (t < EE) {
        const float base = b1_g[t] + sh_basep[t] + sh_basep[EE + t] +
                           sh_basep[2 * EE + t] + sh_basep[3 * EE + t];
        sh_q4[t * 4 + 0] = base;
        sh_q4[t * 4 + 1] = sh_w1e[t];
        sh_q4[t * 4 + 2] = sh_w1e[EE + t];
        sh_q4[t * 4 + 3] = sh_w1e[2 * EE + t];
    }
    __syncthreads();   // barrier 2: jlist/q4 ready.  Hot loop is barrier-free.

    // per-lane register cache of {base,w1e} for this lane's 16 e-values
    f32x4 qa[8], qb[8];
    #pragma unroll
    for (int jj = 0; jj < 8; ++jj) {
        qa[jj] = *(const f32x4*)&sh_q4[(quad * 8 + jj) * 4];
        qb[jj] = *(const f32x4*)&sh_q4[(32 + quad * 8 + jj) * 4];
    }

    const int cnt = sh_cnt;
    const int njt = (cnt + 15) >> 4;

    float sum2[2] = {0.f, 0.f};
    float mm[2]   = {-3.0e38f, -3.0e38f};   // max over j of flip*logit

    for (int jt = 0; jt < njt; ++jt) {
        const int row = jt * 16 + m16;          // < 256 always
        int jl = sh_jlist[row];
        jl = (row < cnt) ? jl : 0;              // clamp stale tail values
        const float4 efv = *(const float4*)&sh_ef4[jl * 4];

        // build A fragments in registers: a0 = e[quad*8..+8), a1 = e[32+quad*8..+8)
        union { short8 s; __hip_bfloat162 h2[4]; } ua, ub;
        #pragma unroll
        for (int p = 0; p < 4; ++p) {
            const f32x4 qa0 = qa[2 * p], qa1 = qa[2 * p + 1];
            const f32x4 qb0 = qb[2 * p], qb1 = qb[2 * p + 1];
            float2 va, vb;
            va.x = fmaxf(fmaf(efv.z, qa0[3], fmaf(efv.y, qa0[2], fmaf(efv.x, qa0[1], qa0[0]))), 0.f);
            va.y = fmaxf(fmaf(efv.z, qa1[3], fmaf(efv.y, qa1[2], fmaf(efv.x, qa1[1], qa1[0]))), 0.f);
            vb.x = fmaxf(fmaf(efv.z, qb0[3], fmaf(efv.y, qb0[2], fmaf(efv.x, qb0[1], qb0[0]))), 0.f);
            vb.y = fmaxf(fmaf(efv.z, qb1[3], fmaf(efv.y, qb1[2], fmaf(efv.x, qb1[1], qb1[0]))), 0.f);
            ua.h2[p] = __float22bfloat162_rn(va);
            ub.h2[p] = __float22bfloat162_rn(vb);
        }

        const bool tail = (jt == njt - 1) && (cnt & 15);
        #pragma unroll
        for (int dt = 0; dt < 2; ++dt) {
            f32x4 acc = {nb2[dt], nb2[dt], nb2[dt], nb2[dt]};
            acc = __builtin_amdgcn_mfma_f32_16x16x32_bf16(ua.s, bfrag[dt][0], acc, 0, 0, 0);
            acc = __builtin_amdgcn_mfma_f32_16x16x32_bf16(ub.s, bfrag[dt][1], acc, 0, 0, 0);
            if (!tail) {
                #pragma unroll
                for (int r = 0; r < 4; ++r) {
                    const float l = acc[r];
                    mm[dt] = fmaxf(mm[dt], l * flip[dt]);
                    sum2[dt] += sigm(l);
                }
            } else {
                #pragma unroll
                for (int r = 0; r < 4; ++r) {
                    const bool v = (jt * 16 + quad * 4 + r) < cnt;
                    const float lx = v ? acc[r] : -3.0e38f;            // sigm -> 0
                    const float pf = v ? acc[r] * flip[dt] : -3.0e38f; // never wins max
                    mm[dt] = fmaxf(mm[dt], pf);
                    sum2[dt] += sigm(lx);
                }
            }
        }
    }

    // cross-quad reduce; sigmoid applied once on the extreme logit (monotone)
    #pragma unroll
    for (int dt = 0; dt < 2; ++dt) {
        float s = sum2[dt], M = mm[dt];
        s += __shfl_xor(s, 16, 64);  s += __shfl_xor(s, 32, 64);
        M  = fmaxf(M,  __shfl_xor(M, 16, 64));  M  = fmaxf(M,  __shfl_xor(M, 32, 64));
        if (quad == 0) {
            const int d = dstripe + 16 * dt + m16;
            const float hd = hd2[dt];
            float mean = 0.f, amax = 0.f;
            if (cnt > 0) {
                mean = hd * s * __fdividef(1.f, (float)cnt);
                amax = hd * sigm(flip[dt] * M);   // flip=+1: max l; flip=-1: min l
            }
            aggf[bi * 256 + d]       = mean;
            aggf[bi * 256 + 128 + d] = amax;
        }
    }
}

// ---------------- Kernel 2: batched update MLP + LayerNorm ----------------
// 16 rows/block, 128 blocks. B-matrices pre-packed bf16 by gate (u1t, u2t).
__global__ __launch_bounds__(256, 2)
void ecgc_upd(const float* __restrict__ h_g,
              const float* __restrict__ aggf,
              const unsigned short* __restrict__ u1t,
              const unsigned short* __restrict__ u2t,
              const float* __restrict__ b3_g,
              const float* __restrict__ b4_g,
              const float* __restrict__ gam_g,
              const float* __restrict__ bet_g,
              float*       __restrict__ out_g)
{
    const int bi0  = blockIdx.x * 16;
    const int t    = threadIdx.x;
    const int lane = t & 63;
    const int w    = t >> 6;
    const int m16  = lane & 15;
    const int quad = lane >> 4;

    __shared__ __align__(16) unsigned short shA[16 * APAD];
    __shared__ __align__(16) unsigned short rbuf[16 * RPAD];
    __shared__ float sh_s[4 * 16], sh_s2[4 * 16], sh_mu[16], sh_rs[16];

    {
        const int row = t >> 4, q = t & 15;
        const float* hrow = h_g  + (size_t)(bi0 + row) * DD;
        const float* wrow = aggf + (size_t)(bi0 + row) * 256;
        unsigned short tmp[24];
        #pragma unroll
        for (int c = 0; c < 24; ++c) {
            const int col = q * 24 + c;
            float v;
            if (col < 128)      v = hrow[col];
            else if (col < 256) v = wrow[col - 128];
            else                v = wrow[col - 256 + 128];
            tmp[c] = f2bf(v);
        }
        #pragma unroll
        for (int s8 = 0; s8 < 3; ++s8)
            *(short8*)&shA[row * APAD + q * 24 + s8 * 8] = *(const short8*)&tmp[s8 * 8];
    }
    __syncthreads();

    const int dstripe = w * 32;

    f32x4 acc[2];
    #pragma unroll
    for (int dt = 0; dt < 2; ++dt) {
        const float bb = b3_g[dstripe + dt * 16 + m16];
        acc[dt] = (f32x4){bb, bb, bb, bb};
    }
    for (int kk = 0; kk < 12; ++kk) {
        const short8 a0 = *(const short8*)&shA[m16 * APAD + kk * 32 + quad * 8];
        #pragma unroll
        for (int dt = 0; dt < 2; ++dt) {
            const int d = dstripe + dt * 16 + m16;
            const short8 b = *(const short8*)&u1t[(size_t)d * 384 + kk * 32 + quad * 8];
            acc[dt] = __builtin_amdgcn_mfma_f32_16x16x32_bf16(a0, b, acc[dt], 0, 0, 0);
        }
    }

    #pragma unroll
    for (int dt = 0; dt < 2; ++dt) {
        const int d = dstripe + dt * 16 + m16;
        #pragma unroll
        for (int r = 0; r < 4; ++r) {
            const int ro = quad * 4 + r;
            rbuf[ro * RPAD + d] = f2bf(fmaxf(acc[dt][r], 0.f));
        }
    }
    __syncthreads();

    f32x4 acc2[2];
    #pragma unroll
    for (int dt = 0; dt < 2; ++dt) {
        const float bb = b4_g[dstripe + dt * 16 + m16];
        acc2[dt] = (f32x4){bb, bb, bb, bb};
    }
    for (int kk = 0; kk < 4; ++kk) {
        const short8 a0 = *(const short8*)&rbuf[m16 * RPAD + kk * 32 + quad * 8];
        #pragma unroll
        for (int dt = 0; dt < 2; ++dt) {
            const int d = dstripe + dt * 16 + m16;
            const short8 b = *(const short8*)&u2t[(size_t)d * 128 + kk * 32 + quad * 8];
            acc2[dt] = __builtin_amdgcn_mfma_f32_16x16x32_bf16(a0, b, acc2[dt], 0, 0, 0);
        }
    }

    float xv[2][4];
    #pragma unroll
    for (int dt = 0; dt < 2; ++dt) {
        const int d = dstripe + dt * 16 + m16;
        #pragma unroll
        for (int r = 0; r < 4; ++r) {
            const int ro = quad * 4 + r;
            xv[dt][r] = h_g[(size_t)(bi0 + ro) * DD + d] + acc2[dt][r];
        }
    }

    #pragma unroll
    for (int r = 0; r < 4; ++r) {
        float s  = xv[0][r] + xv[1][r];
        float s2 = xv[0][r] * xv[0][r] + xv[1][r] * xv[1][r];
        #pragma unroll
        for (int off = 1; off < 16; off <<= 1) {
            s  += __shfl_xor(s,  off, 64);
            s2 += __shfl_xor(s2, off, 64);
        }
        if (m16 == 0) {
            const int ro = quad * 4 + r;
            sh_s[w * 16 + ro]  = s;
            sh_s2[w * 16 + ro] = s2;
        }
    }
    __syncthreads();
    if (t < 16) {
        const float S  = sh_s[t]  + sh_s[16 + t]  + sh_s[32 + t]  + sh_s[48 + t];
        const float S2 = sh_s2[t] + sh_s2[16 + t] + sh_s2[32 + t] + sh_s2[48 + t];
        const float mu  = S * (1.f / 128.f);
        const float var = S2 * (1.f / 128.f) - mu * mu;
        sh_mu[t] = mu;
        sh_rs[t] = rsqrtf(var + 1e-5f);
    }
    __syncthreads();

    #pragma unroll
    for (int dt = 0; dt < 2; ++dt) {
        const int d = dstripe + dt * 16 + m16;
        const float ga = gam_g[d], be = bet_g[d];
        #pragma unroll
        for (int r = 0; r < 4; ++r) {
            const int ro = quad * 4 + r;
            out_g[(size_t)(bi0 + ro) * DD + d] =
                (xv[dt][r] - sh_mu[ro]) * sh_rs[ro] * ga + be;
        }
    }
}

extern "C" void kernel_launch(void* const* d_in, const int* in_sizes, int n_in,
                              void* d_out, int out_size, void* d_ws, size_t ws_size,
                              hipStream_t stream) {
    float* aggf = (float*)d_ws;                                    // 2 MB
    unsigned short* u1t = (unsigned short*)((char*)d_ws + (size_t)2048 * 256 * 4);
    unsigned short* u2t = u1t + 384 * DD;                          // +96 KB
    ecgc_gate<<<8 * NN, 256, 0, stream>>>(
        (const float*)d_in[0],   // h
        (const float*)d_in[1],   // edge_feats
        (const int*)d_in[2],     // adj_mask
        (const float*)d_in[3],   // W1
        (const float*)d_in[4],   // b1
        (const float*)d_in[5],   // W2
        (const float*)d_in[6],   // b2
        (const float*)d_in[7],   // U1
        (const float*)d_in[9],   // U2
        aggf, u1t, u2t);
    ecgc_upd<<<(8 * NN) / 16, 256, 0, stream>>>(
        (const float*)d_in[0],   // h
        aggf, u1t, u2t,
        (const float*)d_in[8],   // b3
        (const float*)d_in[10],  // b4
        (const float*)d_in[11],  // gamma
        (const float*)d_in[12],  // beta
        (float*)d_out);
}